// Round 1
// baseline (242.208 us; speedup 1.0000x reference)
//
#include <hip/hip_runtime.h>

#define NIN 64
#define NOUT 64
#define NTO 16
#define HH 192
#define WW 192
#define HO 190
#define WO 190
#define TILE 64
#define IN_TILE 66
#define LDS_STRIDE 68   // floats; 68*4B = 272B row stride keeps float4 reads 16B-aligned

__global__ __launch_bounds__(256, 2) void scm_kernel(
    const float* __restrict__ x,
    const float* __restrict__ w,
    const float* __restrict__ bias,
    const int* __restrict__ conn_in,
    float* __restrict__ out)
{
    __shared__ float smem[IN_TILE * LDS_STRIDE];

    const int tid = threadIdx.x;
    const int tx = tid & 15;        // col group of 4  -> cols 4*tx .. 4*tx+3
    const int ty = tid >> 4;        // row group of 4  -> rows 4*ty .. 4*ty+3
    const int tilex = blockIdx.x % 3;
    const int tiley = blockIdx.x / 3;
    const int o = blockIdx.y;
    const int b = blockIdx.z;
    const int i0 = tiley * TILE;
    const int j0 = tilex * TILE;

    float acc[4][4];
    #pragma unroll
    for (int i = 0; i < 4; ++i)
        #pragma unroll
        for (int j = 0; j < 4; ++j) acc[i][j] = 0.f;

    const int kbase = o * NTO;

    for (int t = 0; t < NTO; ++t) {
        // block-uniform gather index -> scalar
        const int ci = __builtin_amdgcn_readfirstlane(conn_in[kbase + t]);

        if (t) __syncthreads();     // protect smem from previous iteration's readers
        const float* __restrict__ xc = x + (size_t)(b * NIN + ci) * (HH * WW);
        for (int idx = tid; idx < IN_TILE * IN_TILE; idx += 256) {
            int r = idx / IN_TILE;
            int c = idx - r * IN_TILE;
            int gr = i0 + r, gc = j0 + c;
            float v = 0.f;
            if (gr < HH && gc < WW) v = xc[gr * WW + gc];
            smem[r * LDS_STRIDE + c] = v;
        }
        __syncthreads();

        // block-uniform weights
        float wv[9];
        #pragma unroll
        for (int q = 0; q < 9; ++q)
            wv[q] = w[(kbase + t) * 9 + q];

        #pragma unroll
        for (int r = 0; r < 6; ++r) {
            const int row = ty * 4 + r;
            const float4 v4 = *(const float4*)&smem[row * LDS_STRIDE + tx * 4];
            const float2 v2 = *(const float2*)&smem[row * LDS_STRIDE + tx * 4 + 4];
            const float rowv[6] = {v4.x, v4.y, v4.z, v4.w, v2.x, v2.y};
            #pragma unroll
            for (int i = 0; i < 4; ++i) {
                const int kh = r - i;
                if (kh >= 0 && kh < 3) {
                    #pragma unroll
                    for (int kw = 0; kw < 3; ++kw) {
                        const float wk = wv[kh * 3 + kw];
                        #pragma unroll
                        for (int p = 0; p < 4; ++p)
                            acc[i][p] = fmaf(wk, rowv[p + kw], acc[i][p]);
                    }
                }
            }
        }
    }

    const float bv = bias[o];
    float* outp = out + (size_t)(b * NOUT + o) * (HO * WO);
    #pragma unroll
    for (int i = 0; i < 4; ++i) {
        const int gi = i0 + ty * 4 + i;
        if (gi < HO) {
            const int gj = j0 + tx * 4;
            #pragma unroll
            for (int p = 0; p < 4; ++p)
                if (gj + p < WO) outp[gi * WO + gj + p] = acc[i][p] + bv;
        }
    }
}

extern "C" void kernel_launch(void* const* d_in, const int* in_sizes, int n_in,
                              void* d_out, int out_size, void* d_ws, size_t ws_size,
                              hipStream_t stream) {
    const float* x       = (const float*)d_in[0];
    const float* weight  = (const float*)d_in[1];
    const float* bias    = (const float*)d_in[2];
    const int*   conn_in = (const int*)d_in[3];
    // d_in[4] = conn_out (implicit: k -> k/16)

    dim3 grid(9, NOUT, 4);   // 3x3 tiles of 64x64 covering 190x190, y=out channel, z=batch
    dim3 block(256);
    scm_kernel<<<grid, block, 0, stream>>>(x, weight, bias, conn_in, (float*)d_out);
}

// Round 2
// 111.884 us; speedup vs baseline: 2.1648x; 2.1648x over previous
//
#include <hip/hip_runtime.h>

#define NIN 64
#define NOUT 64
#define NTO 16
#define HH 192
#define WW 192
#define HO 190
#define WO 190
#define LDSTRIDE 68          // floats per LDS row (66 real + 2 pad) -> 272 B
#define BUF_BYTES 20480      // 5 rounds * 256 threads * 16 B (66*68*4=17952 real + pad)

typedef const __attribute__((address_space(1))) void gv_t;
typedef __attribute__((address_space(3))) void lv_t;

__global__ __launch_bounds__(256, 4) void scm_kernel(
    const float* __restrict__ x,
    const float* __restrict__ w,
    const float* __restrict__ bias,
    const int* __restrict__ conn_in,
    float* __restrict__ out)
{
    __shared__ char smem[2 * BUF_BYTES];

    const int tid = threadIdx.x;
    const int tx = tid & 15;        // col group of 4
    const int ty = tid >> 4;        // row group of 4
    const int tilex = blockIdx.x % 3;
    const int tiley = blockIdx.x / 3;
    const int o = blockIdx.y;
    const int b = blockIdx.z;
    const int i0 = tiley * 64;
    const int j0 = tilex * 64;

    // Per-lane global byte offsets for the 5 staging rounds (channel-independent).
    // Linear LDS layout [r][c] stride 68 floats; clamped lanes only feed LDS pad
    // or outputs >= row/col 190 which are discarded.
    int goff[5];
    #pragma unroll
    for (int s = 0; s < 5; ++s) {
        int e = (s * 4096 + tid * 16) >> 2;   // float index in padded linear buffer
        int r = e / LDSTRIDE;
        int c = e - r * LDSTRIDE;
        int gr = i0 + r; if (gr > 191) gr = 191;
        int gc = j0 + c; if (gc > 188) gc = 188;   // keep 16B load within the row
        goff[s] = (gr * WW + gc) * 4;
    }
    const int wid = __builtin_amdgcn_readfirstlane(tid >> 6);
    const char* xb = (const char*)x + (size_t)b * NIN * HH * WW * 4;
    char* lwave = smem + wid * 1024;
    const int kbase = o * NTO;

#define STAGE(ci, buf) do {                                                     \
        const char* _src = xb + (size_t)(ci) * (HH * WW * 4);                   \
        char* _lb = lwave + (buf) * BUF_BYTES;                                  \
        _Pragma("unroll")                                                       \
        for (int _s = 0; _s < 5; ++_s)                                          \
            __builtin_amdgcn_global_load_lds((gv_t*)(_src + goff[_s]),          \
                                             (lv_t*)(_lb + _s * 4096),          \
                                             16, 0, 0);                         \
    } while (0)

    float acc[4][4];
    #pragma unroll
    for (int i = 0; i < 4; ++i)
        #pragma unroll
        for (int p = 0; p < 4; ++p) acc[i][p] = 0.f;

    // prologue: stage channel 0
    {
        const int c0 = __builtin_amdgcn_readfirstlane(conn_in[kbase]);
        STAGE(c0, 0);
    }

    #pragma unroll 1
    for (int t = 0; t < NTO; ++t) {
        const int cur = t & 1;
        if (t < NTO - 1) {
            const int cn = __builtin_amdgcn_readfirstlane(conn_in[kbase + t + 1]);
            STAGE(cn, cur ^ 1);
        }
        float wv[9];
        #pragma unroll
        for (int q = 0; q < 9; ++q) wv[q] = w[(kbase + t) * 9 + q];

        // wait for THIS channel's 5 loads only; keep next channel's 5 in flight
        if (t < NTO - 1) asm volatile("s_waitcnt vmcnt(5)" ::: "memory");
        else             asm volatile("s_waitcnt vmcnt(0)" ::: "memory");
        __builtin_amdgcn_s_barrier();

        const char* rb = smem + cur * BUF_BYTES + ty * 1088 + tx * 16;
        #pragma unroll
        for (int r = 0; r < 6; ++r) {
            const float4 v4 = *(const float4*)(rb + r * 272);
            const float2 v2 = *(const float2*)(rb + r * 272 + 16);
            const float rowv[6] = {v4.x, v4.y, v4.z, v4.w, v2.x, v2.y};
            #pragma unroll
            for (int i = 0; i < 4; ++i) {
                const int kh = r - i;
                if (kh >= 0 && kh < 3) {
                    #pragma unroll
                    for (int kw = 0; kw < 3; ++kw) {
                        const float wk = wv[kh * 3 + kw];
                        #pragma unroll
                        for (int p = 0; p < 4; ++p)
                            acc[i][p] = fmaf(wk, rowv[p + kw], acc[i][p]);
                    }
                }
            }
        }
        // make sure our ds_reads are fully done before anyone restages this buffer
        asm volatile("s_waitcnt lgkmcnt(0)" ::: "memory");
        if (t < NTO - 1) __builtin_amdgcn_s_barrier();
    }
#undef STAGE

    const float bv = bias[o];
    float* outp = out + (size_t)(b * NOUT + o) * (HO * WO);
    #pragma unroll
    for (int i = 0; i < 4; ++i) {
        const int gi = i0 + ty * 4 + i;
        if (gi < HO) {
            const int gj = j0 + tx * 4;
            float* row = outp + (size_t)gi * WO + gj;
            if (gj + 3 < WO) {
                float2 lo = make_float2(acc[i][0] + bv, acc[i][1] + bv);
                float2 hi = make_float2(acc[i][2] + bv, acc[i][3] + bv);
                *(float2*)(row)     = lo;
                *(float2*)(row + 2) = hi;
            } else {
                #pragma unroll
                for (int p = 0; p < 4; ++p)
                    if (gj + p < WO) row[p] = acc[i][p] + bv;
            }
        }
    }
}

extern "C" void kernel_launch(void* const* d_in, const int* in_sizes, int n_in,
                              void* d_out, int out_size, void* d_ws, size_t ws_size,
                              hipStream_t stream) {
    const float* x       = (const float*)d_in[0];
    const float* weight  = (const float*)d_in[1];
    const float* bias    = (const float*)d_in[2];
    const int*   conn_in = (const int*)d_in[3];
    // d_in[4] = conn_out (implicit: k -> k/16)

    dim3 grid(9, NOUT, 4);
    dim3 block(256);
    scm_kernel<<<grid, block, 0, stream>>>(x, weight, bias, conn_in, (float*)d_out);
}

// Round 3
// 76.371 us; speedup vs baseline: 3.1715x; 1.4650x over previous
//
#include <hip/hip_runtime.h>

#define NIN 64
#define NOUT 64
#define NTO 16
#define HH 192
#define WW 192
#define HO 190
#define WO 190
#define LDSTRIDE 68          // floats per LDS row (66 real + 2 pad) -> 272 B
#define BUF_BYTES 20480      // 5 rounds * 256 threads * 16 B (66*68*4=17952 real + pad)
#define NBLK 2304            // 36 groups (9 tiles x 4 batch) x 64 out channels

typedef const __attribute__((address_space(1))) void gv_t;
typedef __attribute__((address_space(3))) void lv_t;

__global__ __launch_bounds__(256, 4) void scm_kernel(
    const float* __restrict__ x,
    const float* __restrict__ w,
    const float* __restrict__ bias,
    const int* __restrict__ conn_in,
    float* __restrict__ out)
{
    __shared__ char smem[2 * BUF_BYTES];

    const int tid = threadIdx.x;
    const int tx = tid & 15;        // col group of 4
    const int ty = tid >> 4;        // row group of 4

    // XCD-aware swizzle: dispatch id -> logical id so each XCD's L2 sees
    // contiguous chunks of 64 o-blocks sharing one x-tile region.
    // nwg=2304 divisible by 8 -> simple bijective form.
    const int lid = (blockIdx.x & 7) * (NBLK / 8) + (blockIdx.x >> 3);
    const int o   = lid & 63;       // o minor: 64 consecutive lids share (tile,b)
    const int g   = lid >> 6;       // 0..35
    const int tile = g % 9;
    const int b    = g / 9;
    const int tilex = tile % 3;
    const int tiley = tile / 3;
    const int i0 = tiley * 64;
    const int j0 = tilex * 64;

    // Per-lane global byte offsets for the 5 staging rounds (channel-independent).
    int goff[5];
    #pragma unroll
    for (int s = 0; s < 5; ++s) {
        int e = (s * 4096 + tid * 16) >> 2;   // float index in padded linear buffer
        int r = e / LDSTRIDE;
        int c = e - r * LDSTRIDE;
        int gr = i0 + r; if (gr > 191) gr = 191;
        int gc = j0 + c; if (gc > 188) gc = 188;   // keep 16B load within the row
        goff[s] = (gr * WW + gc) * 4;
    }
    const int wid = __builtin_amdgcn_readfirstlane(tid >> 6);
    const char* xb = (const char*)x + (size_t)b * NIN * HH * WW * 4;
    char* lwave = smem + wid * 1024;
    const int kbase = o * NTO;

#define STAGE(ci, buf) do {                                                     \
        const char* _src = xb + (size_t)(ci) * (HH * WW * 4);                   \
        char* _lb = lwave + (buf) * BUF_BYTES;                                  \
        _Pragma("unroll")                                                       \
        for (int _s = 0; _s < 5; ++_s)                                          \
            __builtin_amdgcn_global_load_lds((gv_t*)(_src + goff[_s]),          \
                                             (lv_t*)(_lb + _s * 4096),          \
                                             16, 0, 0);                         \
    } while (0)

    float acc[4][4];
    #pragma unroll
    for (int i = 0; i < 4; ++i)
        #pragma unroll
        for (int p = 0; p < 4; ++p) acc[i][p] = 0.f;

    // prologue: stage channel 0
    {
        const int c0 = __builtin_amdgcn_readfirstlane(conn_in[kbase]);
        STAGE(c0, 0);
    }

    #pragma unroll 1
    for (int t = 0; t < NTO; ++t) {
        const int cur = t & 1;
        if (t < NTO - 1) {
            const int cn = __builtin_amdgcn_readfirstlane(conn_in[kbase + t + 1]);
            STAGE(cn, cur ^ 1);
        }
        float wv[9];
        #pragma unroll
        for (int q = 0; q < 9; ++q) wv[q] = w[(kbase + t) * 9 + q];

        // wait for THIS channel's 5 loads only; keep next channel's 5 in flight
        if (t < NTO - 1) asm volatile("s_waitcnt vmcnt(5)" ::: "memory");
        else             asm volatile("s_waitcnt vmcnt(0)" ::: "memory");
        __builtin_amdgcn_s_barrier();

        const char* rb = smem + cur * BUF_BYTES + ty * 1088 + tx * 16;
        #pragma unroll
        for (int r = 0; r < 6; ++r) {
            const float4 v4 = *(const float4*)(rb + r * 272);
            const float2 v2 = *(const float2*)(rb + r * 272 + 16);
            const float rowv[6] = {v4.x, v4.y, v4.z, v4.w, v2.x, v2.y};
            #pragma unroll
            for (int i = 0; i < 4; ++i) {
                const int kh = r - i;
                if (kh >= 0 && kh < 3) {
                    #pragma unroll
                    for (int kw = 0; kw < 3; ++kw) {
                        const float wk = wv[kh * 3 + kw];
                        #pragma unroll
                        for (int p = 0; p < 4; ++p)
                            acc[i][p] = fmaf(wk, rowv[p + kw], acc[i][p]);
                    }
                }
            }
        }
        // make sure our ds_reads are fully done before anyone restages this buffer
        asm volatile("s_waitcnt lgkmcnt(0)" ::: "memory");
        if (t < NTO - 1) __builtin_amdgcn_s_barrier();
    }
#undef STAGE

    const float bv = bias[o];
    float* outp = out + (size_t)(b * NOUT + o) * (HO * WO);
    #pragma unroll
    for (int i = 0; i < 4; ++i) {
        const int gi = i0 + ty * 4 + i;
        if (gi < HO) {
            const int gj = j0 + tx * 4;
            float* row = outp + (size_t)gi * WO + gj;
            if (gj + 3 < WO) {
                float2 lo = make_float2(acc[i][0] + bv, acc[i][1] + bv);
                float2 hi = make_float2(acc[i][2] + bv, acc[i][3] + bv);
                *(float2*)(row)     = lo;
                *(float2*)(row + 2) = hi;
            } else {
                #pragma unroll
                for (int p = 0; p < 4; ++p)
                    if (gj + p < WO) row[p] = acc[i][p] + bv;
            }
        }
    }
}

extern "C" void kernel_launch(void* const* d_in, const int* in_sizes, int n_in,
                              void* d_out, int out_size, void* d_ws, size_t ws_size,
                              hipStream_t stream) {
    const float* x       = (const float*)d_in[0];
    const float* weight  = (const float*)d_in[1];
    const float* bias    = (const float*)d_in[2];
    const int*   conn_in = (const int*)d_in[3];
    // d_in[4] = conn_out (implicit: k -> k/16)

    dim3 grid(NBLK);
    dim3 block(256);
    scm_kernel<<<grid, block, 0, stream>>>(x, weight, bias, conn_in, (float*)d_out);
}